// Round 1
// baseline (243.351 us; speedup 1.0000x reference)
//
#include <hip/hip_runtime.h>
#include <hip/hip_bf16.h>

// Problem constants
#define B   256
#define N   100
#define D   768
#define R   80
#define THRESHOLD 0.5f

// Output layout (flat float32 offsets, in return order)
#define SZ_VIS   ((long)B * R * D)           // 15,728,640
#define OFF_VIS  0L
#define OFF_TXT  (OFF_VIS + SZ_VIS)          // 15,728,640
#define OFF_TMASK (OFF_TXT + SZ_VIS)         // 31,457,280
#define OFF_IMASK (OFF_TMASK + (long)B*(R+1))// 31,478,016
#define OFF_RR    (OFF_IMASK + (long)B*(R+1))// 31,498,752
#define OFF_LAB   (OFF_RR + (long)B*R)       // 31,519,232

// Kernel 1: per-batch control logic + small outputs.
// One block per batch (b = blockIdx.x), 128 threads.
__global__ __launch_bounds__(128) void prep_kernel(
    const float* __restrict__ rr_in,    // (B, N)
    const float* __restrict__ lab_in,   // (B, N)
    float* __restrict__ out,
    int* __restrict__ order,            // (B, R) workspace
    int* __restrict__ counts)           // (B,)   workspace
{
    const int b = blockIdx.x;
    const int t = threadIdx.x;

    __shared__ float rrs[R];
    __shared__ int   bin[R];
    __shared__ int   cnt_s;
    __shared__ int   zero_s;

    if (t < R) {
        float v = rr_in[b * N + t];
        rrs[t] = v;
        bin[t] = (v > THRESHOLD) ? 1 : 0;
        out[OFF_LAB + (long)b * R + t] = lab_in[b * N + t];
    }
    __syncthreads();

    if (t == 0) {
        // Stable partition: selected (binary==1) indices first, original order,
        // then unselected. Matches stable argsort of (1 - binary).
        int c = 0;
        for (int i = 0; i < R; ++i)
            if (bin[i]) order[b * R + c++] = i;
        int p = c;
        for (int i = 0; i < R; ++i)
            if (!bin[i]) order[b * R + p++] = i;
        cnt_s = c;
        counts[b] = c;
        // zero_rows: all(rr_mod == 0) where rr_mod = (rr < 0.5 ? 0 : rr)
        int allz = 1;
        for (int i = 0; i < R; ++i) {
            float rm = (rrs[i] < THRESHOLD) ? 0.0f : rrs[i];
            if (rm != 0.0f) { allz = 0; break; }
        }
        zero_s = allz;
    }
    __syncthreads();

    const int cnt = cnt_s;
    if (t < R) {
        float v = rrs[t];
        float rm = (v < THRESHOLD) ? 0.0f : v;
        if (t == 0 && zero_s) rm = 1.0f;
        out[OFF_RR + (long)b * R + t] = rm;
    }
    if (t <= R) {  // R+1 = 81 mask entries
        float tm = (t <= cnt) ? 1.0f : 0.0f;
        out[OFF_TMASK + (long)b * (R + 1) + t] = tm;
        float im = (b == B - 1) ? tm : 1.0f;
        out[OFF_IMASK + (long)b * (R + 1) + t] = im;
    }
}

// Kernel 2: packed gather of vis & txt rows.
// One block per output row (B*R blocks), 192 threads; each thread moves one
// float4 (16 B) from each tensor. Rows are 3072 B contiguous -> coalesced.
__global__ __launch_bounds__(192) void gather_kernel(
    const float* __restrict__ vis,   // (B, N, 1, D)
    const float* __restrict__ txt,   // (B, N, 1, D)
    float* __restrict__ out,
    const int* __restrict__ order,
    const int* __restrict__ counts)
{
    const int row = blockIdx.x;        // 0 .. B*R-1
    const int b = row / R;
    const int r = row - b * R;
    const int t = threadIdx.x;         // 0 .. 191 (D/4 = 192)

    float4 v = make_float4(0.f, 0.f, 0.f, 0.f);
    float4 x = v;
    if (r < counts[b]) {               // uniform per block
        const int src = order[b * R + r];
        const long in_idx = ((long)b * N + src) * D + t * 4;
        v = *(const float4*)(vis + in_idx);
        x = *(const float4*)(txt + in_idx);
    }
    const long o = ((long)b * R + r) * D + t * 4;
    *(float4*)(out + OFF_VIS + o) = v;
    *(float4*)(out + OFF_TXT + o) = x;
}

extern "C" void kernel_launch(void* const* d_in, const int* in_sizes, int n_in,
                              void* d_out, int out_size, void* d_ws, size_t ws_size,
                              hipStream_t stream) {
    // inputs (setup_inputs order):
    // 0: mean_pooling_vec (B,D)        -- unused
    // 1: merge_text_vec (B,D)          -- unused
    // 2: retrieved_visual_feature_embedding_cls (B,N,1,D)
    // 3: retrieved_textual_feature_embedding    (B,N,1,D)
    // 4: retrieved_label_list (B,N)
    // 5: RRCP (B,N)
    const float* vis = (const float*)d_in[2];
    const float* txt = (const float*)d_in[3];
    const float* lab = (const float*)d_in[4];
    const float* rr  = (const float*)d_in[5];
    float* out = (float*)d_out;

    int* order  = (int*)d_ws;            // B*R ints
    int* counts = order + B * R;         // B ints

    prep_kernel<<<B, 128, 0, stream>>>(rr, lab, out, order, counts);
    gather_kernel<<<B * R, 192, 0, stream>>>(vis, txt, out, order, counts);
}

// Round 2
// 240.990 us; speedup vs baseline: 1.0098x; 1.0098x over previous
//
#include <hip/hip_runtime.h>
#include <hip/hip_bf16.h>

// Problem constants
#define B   256
#define N   100
#define D   768
#define R   80
#define RPB 8            // rows handled per block
#define THRESHOLD 0.5f

// Output layout (flat float32 offsets, in return order)
#define SZ_VIS    ((long)B * R * D)            // 15,728,640
#define OFF_VIS   0L
#define OFF_TXT   (OFF_VIS + SZ_VIS)           // 15,728,640
#define OFF_TMASK (OFF_TXT + SZ_VIS)           // 31,457,280
#define OFF_IMASK (OFF_TMASK + (long)B*(R+1))  // 31,478,016
#define OFF_RR    (OFF_IMASK + (long)B*(R+1))  // 31,498,752
#define OFF_LAB   (OFF_RR + (long)B*R)         // 31,519,232

// Single fused kernel.
// grid = (R/RPB, B) = (10, 256); block = 192 threads (D/4 float4 lanes).
// Each block:
//   - loads its batch's 80 rr values into LDS (320 B, L2-resident across the
//     10 blocks of a batch)
//   - thread 0 scans once to get count + the order indices for its 8 rows
//     (stable partition == stable argsort of (1-binary))
//   - copies 8 rows of vis & txt (float4 per thread, fully coalesced), or
//     writes zeros for rows past count
//   - the blockIdx.x==0 block additionally emits the small outputs
__global__ __launch_bounds__(192) void fused_kernel(
    const float* __restrict__ vis,    // (B, N, 1, D)
    const float* __restrict__ txt,    // (B, N, 1, D)
    const float* __restrict__ lab_in, // (B, N)
    const float* __restrict__ rr_in,  // (B, N)
    float* __restrict__ out)
{
    const int b  = blockIdx.y;
    const int r0 = blockIdx.x * RPB;
    const int t  = threadIdx.x;

    __shared__ float rrs[R];
    __shared__ int   order_s[RPB];
    __shared__ int   cnt_s;
    __shared__ int   zero_s;

    if (t < R) rrs[t] = rr_in[b * N + t];
    __syncthreads();

    if (t == 0) {
        int c = 0;
        int allz = 1;   // zero_rows <=> all rr < 0.5 (rr>=0.5 -> rr_mod=rr!=0)
        for (int i = 0; i < R; ++i) {
            float v = rrs[i];
            if (v >= THRESHOLD) allz = 0;
            if (v > THRESHOLD) {
                int rel = c - r0;
                if (rel >= 0 && rel < RPB) order_s[rel] = i;
                c++;
            }
        }
        cnt_s  = c;
        zero_s = allz;
    }
    __syncthreads();

    const int cnt = cnt_s;

    // Main copy: 8 rows, thread t owns float4 column t. Unrolled for MLP.
    #pragma unroll
    for (int j = 0; j < RPB; ++j) {
        const int r = r0 + j;
        float4 v = make_float4(0.f, 0.f, 0.f, 0.f);
        float4 x = v;
        if (r < cnt) {                 // uniform across the block's row j
            const long in_idx = ((long)b * N + order_s[j]) * D + t * 4;
            v = *(const float4*)(vis + in_idx);
            x = *(const float4*)(txt + in_idx);
        }
        const long o = ((long)b * R + r) * D + t * 4;
        *(float4*)(out + OFF_VIS + o) = v;
        *(float4*)(out + OFF_TXT + o) = x;
    }

    // Small outputs: one block per batch handles them.
    if (r0 == 0) {
        if (t < R) {
            out[OFF_LAB + (long)b * R + t] = lab_in[b * N + t];
            float v  = rrs[t];
            float rm = (v < THRESHOLD) ? 0.0f : v;
            if (t == 0 && zero_s) rm = 1.0f;
            out[OFF_RR + (long)b * R + t] = rm;
        }
        if (t <= R) {  // R+1 = 81 mask entries
            float tm = (t <= cnt) ? 1.0f : 0.0f;
            out[OFF_TMASK + (long)b * (R + 1) + t] = tm;
            out[OFF_IMASK + (long)b * (R + 1) + t] = (b == B - 1) ? tm : 1.0f;
        }
    }
}

extern "C" void kernel_launch(void* const* d_in, const int* in_sizes, int n_in,
                              void* d_out, int out_size, void* d_ws, size_t ws_size,
                              hipStream_t stream) {
    // inputs (setup_inputs order):
    // 0: mean_pooling_vec (B,D)        -- unused
    // 1: merge_text_vec (B,D)          -- unused
    // 2: retrieved_visual_feature_embedding_cls (B,N,1,D)
    // 3: retrieved_textual_feature_embedding    (B,N,1,D)
    // 4: retrieved_label_list (B,N)
    // 5: RRCP (B,N)
    const float* vis = (const float*)d_in[2];
    const float* txt = (const float*)d_in[3];
    const float* lab = (const float*)d_in[4];
    const float* rr  = (const float*)d_in[5];
    float* out = (float*)d_out;

    dim3 grid(R / RPB, B);   // (10, 256)
    fused_kernel<<<grid, 192, 0, stream>>>(vis, txt, lab, rr, out);
}